// Round 3
// baseline (81.064 us; speedup 1.0000x reference)
//
#include <hip/hip_runtime.h>
#include <stdint.h>

#define BB 8
#define CC 19
#define HH 512
#define WW 1024
#define KK 15
#define RR 7
#define TH 8
#define NROWS (TH + 2*RR)          // 22 staged rows
#define ROW_DW 260                 // 2 pad dw + 256 data dw + 2 pad dw
#define NPIX (BB*HH*WW)            // 4194304
#define HW (HH*WW)
#define NBLK (BB*(HH/TH))          // 512
#define SENT4 0x1F1F1F1Fu          // sentinel class 31: xor with 0..18 stays in [1,31]

static __device__ __forceinline__ uint32_t alignb(uint32_t hi, uint32_t lo, unsigned s) {
#if __has_builtin(__builtin_amdgcn_alignbyte)
  return __builtin_amdgcn_alignbyte(hi, lo, s);
#else
  return (uint32_t)(((((uint64_t)hi) << 32) | lo) >> (8u * s));
#endif
}

__global__ __launch_bounds__(256) void wce_main(const float* __restrict__ in,
                                                const int* __restrict__ tg,
                                                float* __restrict__ wsF,
                                                float* __restrict__ out) {
  __shared__ uint32_t T[NROWS][ROW_DW];
  __shared__ float wpart[4];
  const int tid = threadIdx.x;
  const int blk = blockIdx.x;
  const int bb  = blk >> 6;           // 64 h-blocks per batch (512/TH)
  const int h0  = (blk & 63) * TH;

  // ---- stage 22 target rows as packed bytes with sentinel padding ----
  const int total = NROWS * ROW_DW;
  for (int idx = tid; idx < total; idx += 256) {
    const int r = idx / ROW_DW;
    const int d = idx - r * ROW_DW;
    uint32_t v = SENT4;
    const int h = h0 - RR + r;
    if (h >= 0 && h < HH && d >= 2 && d < 258) {
      const int4 t4 = *reinterpret_cast<const int4*>(&tg[(bb*HH + h)*WW + (d - 2)*4]);
      v = (uint32_t)(t4.x & 0xff)        | ((uint32_t)(t4.y & 0xff) << 8)
        | ((uint32_t)(t4.z & 0xff) << 16) | ((uint32_t)(t4.w & 0xff) << 24);
    }
    (&T[0][0])[idx] = v;
  }
  __syncthreads();

  const int g = tid;                  // this thread's 4-px group: w = 4g..4g+3
  const int gbase = bb*CC*HW + h0*WW + 4*g;
  float acc = 0.0f;

  // SWAR window body for step s with center classes c4; adds to acc using x0..x3
  #define WINDOW(s_, c4_, x0_, x1_, x2_, x3_) do {                              \
    uint32_t nm = 0;                                                            \
    _Pragma("unroll")                                                           \
    for (int wr = 0; wr < KK; ++wr) {                                           \
      const uint32_t* row = &T[(s_) + wr][g];                                   \
      const uint32_t d0 = row[0], d1 = row[1], d2 = row[2], d3 = row[3], d4 = row[4]; \
      uint32_t t_;                                                              \
      t_ = (alignb(d1, d0, 1) ^ (c4_)) + 0x7f7f7f7fu; nm += (t_ & 0x80808080u) >> 7; \
      t_ = (alignb(d1, d0, 2) ^ (c4_)) + 0x7f7f7f7fu; nm += (t_ & 0x80808080u) >> 7; \
      t_ = (alignb(d1, d0, 3) ^ (c4_)) + 0x7f7f7f7fu; nm += (t_ & 0x80808080u) >> 7; \
      t_ = (d1              ^ (c4_)) + 0x7f7f7f7fu; nm += (t_ & 0x80808080u) >> 7; \
      t_ = (alignb(d2, d1, 1) ^ (c4_)) + 0x7f7f7f7fu; nm += (t_ & 0x80808080u) >> 7; \
      t_ = (alignb(d2, d1, 2) ^ (c4_)) + 0x7f7f7f7fu; nm += (t_ & 0x80808080u) >> 7; \
      t_ = (alignb(d2, d1, 3) ^ (c4_)) + 0x7f7f7f7fu; nm += (t_ & 0x80808080u) >> 7; \
      t_ = (d2              ^ (c4_)) + 0x7f7f7f7fu; nm += (t_ & 0x80808080u) >> 7; \
      t_ = (alignb(d3, d2, 1) ^ (c4_)) + 0x7f7f7f7fu; nm += (t_ & 0x80808080u) >> 7; \
      t_ = (alignb(d3, d2, 2) ^ (c4_)) + 0x7f7f7f7fu; nm += (t_ & 0x80808080u) >> 7; \
      t_ = (alignb(d3, d2, 3) ^ (c4_)) + 0x7f7f7f7fu; nm += (t_ & 0x80808080u) >> 7; \
      t_ = (d3              ^ (c4_)) + 0x7f7f7f7fu; nm += (t_ & 0x80808080u) >> 7; \
      t_ = (alignb(d4, d3, 1) ^ (c4_)) + 0x7f7f7f7fu; nm += (t_ & 0x80808080u) >> 7; \
      t_ = (alignb(d4, d3, 2) ^ (c4_)) + 0x7f7f7f7fu; nm += (t_ & 0x80808080u) >> 7; \
      t_ = (alignb(d4, d3, 3) ^ (c4_)) + 0x7f7f7f7fu; nm += (t_ & 0x80808080u) >> 7; \
    }                                                                           \
    acc += (x0_) * (225.0f / (float)(225 - (int)( nm        & 0xff)));          \
    acc += (x1_) * (225.0f / (float)(225 - (int)((nm >> 8)  & 0xff)));          \
    acc += (x2_) * (225.0f / (float)(225 - (int)((nm >> 16) & 0xff)));          \
    acc += (x3_) * (225.0f / (float)(225 - (int)((nm >> 24) & 0xff)));          \
  } while (0)

  #define GATHER(s_, c4_, x0_, x1_, x2_, x3_) do {                              \
    (c4_) = T[(s_) + RR][g + 2];                                                \
    const int b_ = gbase + (s_)*WW;                                             \
    (x0_) = in[b_ + (int)( (c4_)        & 0xff)*HW + 0];                        \
    (x1_) = in[b_ + (int)(((c4_) >> 8)  & 0xff)*HW + 1];                        \
    (x2_) = in[b_ + (int)(((c4_) >> 16) & 0xff)*HW + 2];                        \
    (x3_) = in[b_ + (int)(((c4_) >> 24) & 0xff)*HW + 3];                        \
  } while (0)

  // ---- depth-1 branch-free pipeline over TH=8 steps (unrolled by 2) ----
  uint32_t c4a, c4b;
  float a0, a1, a2, a3, b0, b1, b2, b3;
  GATHER(0, c4a, a0, a1, a2, a3);

  #pragma unroll 1
  for (int s = 0; s < TH; s += 2) {
    GATHER(s + 1, c4b, b0, b1, b2, b3);            // issue next-step loads
    WINDOW(s, c4a, a0, a1, a2, a3);                // compute under them
    const int s2 = (s + 2 < TH) ? s + 2 : s;       // last iter: harmless redundant reload
    GATHER(s2, c4a, a0, a1, a2, a3);
    WINDOW(s + 1, c4b, b0, b1, b2, b3);
  }
  #undef GATHER
  #undef WINDOW

  // ---- block reduction ----
  #pragma unroll
  for (int off = 32; off > 0; off >>= 1) acc += __shfl_down(acc, off, 64);
  const int lane = tid & 63, wv = tid >> 6;
  if (lane == 0) wpart[wv] = acc;
  __syncthreads();

  // ---- fused global finish: atomic accumulate, last block writes out ----
  if (tid == 0) {
    const float bsum = wpart[0] + wpart[1] + wpart[2] + wpart[3];
    atomicAdd(&wsF[0], bsum);
    __threadfence();
    const int old = atomicAdd((int*)&wsF[1], 1);
    if (old == NBLK - 1) {
      __threadfence();
      const float tot = __hip_atomic_load(&wsF[0], __ATOMIC_RELAXED, __HIP_MEMORY_SCOPE_AGENT);
      out[0] = -tot / (float)NPIX;
    }
  }
}

extern "C" void kernel_launch(void* const* d_in, const int* in_sizes, int n_in,
                              void* d_out, int out_size, void* d_ws, size_t ws_size,
                              hipStream_t stream) {
  const float* in = (const float*)d_in[0];
  const int*   tg = (const int*)d_in[1];
  float* out = (float*)d_out;
  float* ws  = (float*)d_ws;

  hipMemsetAsync(d_ws, 0, 8, stream);   // zero accumulator + counter each call
  wce_main<<<NBLK, 256, 0, stream>>>(in, tg, ws, out);
}

// Round 4
// 80.911 us; speedup vs baseline: 1.0019x; 1.0019x over previous
//
#include <hip/hip_runtime.h>
#include <stdint.h>

#define BB 8
#define CC 19
#define HH 512
#define WW 1024
#define KK 15
#define RR 7
#define TH 8
#define NROWS (TH + 2*RR)          // 22 staged rows
#define ROW_DW 260                 // 2 pad dw + 256 data dw + 2 pad dw
#define NPIX (BB*HH*WW)            // 4194304
#define HW (HH*WW)
#define NBLK (BB*(HH/TH))          // 512
#define SENT4 0x1F1F1F1Fu          // sentinel class 31: xor with 0..18 stays in [1,31]

static __device__ __forceinline__ uint32_t alignb(uint32_t hi, uint32_t lo, unsigned s) {
#if __has_builtin(__builtin_amdgcn_alignbyte)
  return __builtin_amdgcn_alignbyte(hi, lo, s);
#else
  return (uint32_t)(((((uint64_t)hi) << 32) | lo) >> (8u * s));
#endif
}

__global__ __launch_bounds__(256) void wce_main(const float* __restrict__ in,
                                                const int* __restrict__ tg,
                                                float* __restrict__ wsF,
                                                float* __restrict__ out) {
  __shared__ uint32_t T[NROWS][ROW_DW];
  __shared__ float wpart[4];
  __shared__ int lastFlag;
  const int tid = threadIdx.x;
  const int blk = blockIdx.x;
  const int bb  = blk >> 6;           // 64 h-blocks per batch (512/TH)
  const int h0  = (blk & 63) * TH;

  // ---- stage 22 target rows as packed bytes with sentinel padding ----
  const int total = NROWS * ROW_DW;
  for (int idx = tid; idx < total; idx += 256) {
    const int r = idx / ROW_DW;
    const int d = idx - r * ROW_DW;
    uint32_t v = SENT4;
    const int h = h0 - RR + r;
    if (h >= 0 && h < HH && d >= 2 && d < 258) {
      const int4 t4 = *reinterpret_cast<const int4*>(&tg[(bb*HH + h)*WW + (d - 2)*4]);
      v = (uint32_t)(t4.x & 0xff)        | ((uint32_t)(t4.y & 0xff) << 8)
        | ((uint32_t)(t4.z & 0xff) << 16) | ((uint32_t)(t4.w & 0xff) << 24);
    }
    (&T[0][0])[idx] = v;
  }
  __syncthreads();

  const int g = tid;                  // this thread's 4-px group: w = 4g..4g+3
  float acc = 0.0f;

  #pragma unroll 1
  for (int s = 0; s < TH; ++s) {
    const int hh = h0 + s;
    const uint32_t c4 = T[s + RR][g + 2];   // center classes, packed bytes

    // issue the 4 input gathers early; they drain under the window compute
    const int c0 = (int)(c4 & 0xff), c1 = (int)((c4 >> 8) & 0xff);
    const int c2 = (int)((c4 >> 16) & 0xff), c3 = (int)((c4 >> 24) & 0xff);
    const int base = bb*CC*HW + hh*WW + 4*g;
    const float x0 = in[base + c0*HW + 0];
    const float x1 = in[base + c1*HW + 1];
    const float x2 = in[base + c2*HW + 2];
    const float x3 = in[base + c3*HW + 3];

    // ---- SWAR non-match count over the 15x15 window ----
    uint32_t nm = 0;
    #pragma unroll
    for (int wr = 0; wr < KK; ++wr) {
      const uint32_t* row = &T[s + wr][g];  // dwords g..g+4 cover w = 4g-8 .. 4g+11
      const uint32_t d0 = row[0], d1 = row[1], d2 = row[2], d3 = row[3], d4 = row[4];
      #define CMPW(rhs) do { uint32_t t_ = ((rhs) ^ c4) + 0x7f7f7f7fu; \
                             nm += (t_ & 0x80808080u) >> 7; } while (0)
      CMPW(alignb(d1, d0, 1));   // dw = -7
      CMPW(alignb(d1, d0, 2));   // dw = -6
      CMPW(alignb(d1, d0, 3));   // dw = -5
      CMPW(d1);                  // dw = -4
      CMPW(alignb(d2, d1, 1));   // dw = -3
      CMPW(alignb(d2, d1, 2));   // dw = -2
      CMPW(alignb(d2, d1, 3));   // dw = -1
      CMPW(d2);                  // dw =  0
      CMPW(alignb(d3, d2, 1));   // dw = +1
      CMPW(alignb(d3, d2, 2));   // dw = +2
      CMPW(alignb(d3, d2, 3));   // dw = +3
      CMPW(d3);                  // dw = +4
      CMPW(alignb(d4, d3, 1));   // dw = +5
      CMPW(alignb(d4, d3, 2));   // dw = +6
      CMPW(alignb(d4, d3, 3));   // dw = +7
      #undef CMPW
    }
    const int n0 = 225 - (int)( nm        & 0xff);
    const int n1 = 225 - (int)((nm >> 8)  & 0xff);
    const int n2 = 225 - (int)((nm >> 16) & 0xff);
    const int n3 = 225 - (int)((nm >> 24) & 0xff);
    acc += x0 * (225.0f / (float)n0);
    acc += x1 * (225.0f / (float)n1);
    acc += x2 * (225.0f / (float)n2);
    acc += x3 * (225.0f / (float)n3);
  }

  // ---- block reduction ----
  #pragma unroll
  for (int off = 32; off > 0; off >>= 1) acc += __shfl_down(acc, off, 64);
  const int lane = tid & 63, wv = tid >> 6;
  if (lane == 0) wpart[wv] = acc;
  __syncthreads();

  // ---- fused finish: publish partial, last block reduces deterministically ----
  // ws layout: wsF[0] = int counter (zeroed by hipMemsetAsync), wsF[1..NBLK] = partials
  if (tid == 0) {
    const float bsum = wpart[0] + wpart[1] + wpart[2] + wpart[3];
    __hip_atomic_store(&wsF[1 + blk], bsum, __ATOMIC_RELAXED, __HIP_MEMORY_SCOPE_AGENT);
    const int old = __hip_atomic_fetch_add((int*)&wsF[0], 1, __ATOMIC_ACQ_REL,
                                           __HIP_MEMORY_SCOPE_AGENT);
    lastFlag = (old == NBLK - 1) ? 1 : 0;
  }
  __syncthreads();
  if (lastFlag) {
    // fixed-order reduction over the 512 partials: deterministic across replays
    float a = 0.0f;
    for (int i = tid; i < NBLK; i += 256)
      a += __hip_atomic_load(&wsF[1 + i], __ATOMIC_RELAXED, __HIP_MEMORY_SCOPE_AGENT);
    #pragma unroll
    for (int off = 32; off > 0; off >>= 1) a += __shfl_down(a, off, 64);
    if (lane == 0) wpart[wv] = a;
    __syncthreads();
    if (tid == 0) {
      const float tot = wpart[0] + wpart[1] + wpart[2] + wpart[3];
      out[0] = -tot / (float)NPIX;
    }
  }
}

extern "C" void kernel_launch(void* const* d_in, const int* in_sizes, int n_in,
                              void* d_out, int out_size, void* d_ws, size_t ws_size,
                              hipStream_t stream) {
  const float* in = (const float*)d_in[0];
  const int*   tg = (const int*)d_in[1];
  float* out = (float*)d_out;
  float* ws  = (float*)d_ws;

  hipMemsetAsync(d_ws, 0, 4, stream);   // zero the arrival counter each call
  wce_main<<<NBLK, 256, 0, stream>>>(in, tg, ws, out);
}

// Round 5
// 60.217 us; speedup vs baseline: 1.3462x; 1.3437x over previous
//
#include <hip/hip_runtime.h>
#include <stdint.h>

#define BB 8
#define CC 19
#define HH 512
#define WW 1024
#define KK 15
#define RR 7
#define TH 4
#define NROWS (TH + 2*RR)          // 18 staged rows
#define ROW_DW 260                 // 2 pad dw + 256 data dw + 2 pad dw
#define NPIX (BB*HH*WW)            // 4194304
#define HW (HH*WW)
#define NBLK (BB*(HH/TH))          // 1024
#define SENT4 0x1F1F1F1Fu          // sentinel class 31: xor with 0..18 stays in [1,31]

static __device__ __forceinline__ uint32_t alignb(uint32_t hi, uint32_t lo, unsigned s) {
#if __has_builtin(__builtin_amdgcn_alignbyte)
  return __builtin_amdgcn_alignbyte(hi, lo, s);
#else
  return (uint32_t)(((((uint64_t)hi) << 32) | lo) >> (8u * s));
#endif
}

__global__ __launch_bounds__(256) void wce_main(const float* __restrict__ in,
                                                const int* __restrict__ tg,
                                                float* __restrict__ part) {
  __shared__ uint32_t T[NROWS][ROW_DW];
  __shared__ float wpart[4];
  const int tid = threadIdx.x;
  const int blk = blockIdx.x;
  const int bb  = blk >> 7;           // 128 h-blocks per batch (512/TH)
  const int h0  = (blk & 127) * TH;

  // ---- stage 18 target rows as packed bytes with sentinel padding ----
  const int total = NROWS * ROW_DW;
  for (int idx = tid; idx < total; idx += 256) {
    const int r = idx / ROW_DW;
    const int d = idx - r * ROW_DW;
    uint32_t v = SENT4;
    const int h = h0 - RR + r;
    if (h >= 0 && h < HH && d >= 2 && d < 258) {
      const int4 t4 = *reinterpret_cast<const int4*>(&tg[(bb*HH + h)*WW + (d - 2)*4]);
      v = (uint32_t)(t4.x & 0xff)        | ((uint32_t)(t4.y & 0xff) << 8)
        | ((uint32_t)(t4.z & 0xff) << 16) | ((uint32_t)(t4.w & 0xff) << 24);
    }
    (&T[0][0])[idx] = v;
  }
  __syncthreads();

  const int g = tid;                  // this thread's 4-px group: w = 4g..4g+3
  float acc = 0.0f;

  #pragma unroll 1
  for (int s = 0; s < TH; ++s) {
    const int hh = h0 + s;
    const uint32_t c4 = T[s + RR][g + 2];   // center classes, packed bytes

    // issue the 4 input gathers early; they drain under the window compute
    const int c0 = (int)(c4 & 0xff), c1 = (int)((c4 >> 8) & 0xff);
    const int c2 = (int)((c4 >> 16) & 0xff), c3 = (int)((c4 >> 24) & 0xff);
    const int base = bb*CC*HW + hh*WW + 4*g;
    const float x0 = in[base + c0*HW + 0];
    const float x1 = in[base + c1*HW + 1];
    const float x2 = in[base + c2*HW + 2];
    const float x3 = in[base + c3*HW + 3];

    // ---- SWAR non-match count over the 15x15 window ----
    uint32_t nm = 0;
    #pragma unroll
    for (int wr = 0; wr < KK; ++wr) {
      const uint32_t* row = &T[s + wr][g];  // dwords g..g+4 cover w = 4g-8 .. 4g+11
      const uint32_t d0 = row[0], d1 = row[1], d2 = row[2], d3 = row[3], d4 = row[4];
      #define CMPW(rhs) do { uint32_t t_ = ((rhs) ^ c4) + 0x7f7f7f7fu; \
                             nm += (t_ & 0x80808080u) >> 7; } while (0)
      CMPW(alignb(d1, d0, 1));   // dw = -7
      CMPW(alignb(d1, d0, 2));   // dw = -6
      CMPW(alignb(d1, d0, 3));   // dw = -5
      CMPW(d1);                  // dw = -4
      CMPW(alignb(d2, d1, 1));   // dw = -3
      CMPW(alignb(d2, d1, 2));   // dw = -2
      CMPW(alignb(d2, d1, 3));   // dw = -1
      CMPW(d2);                  // dw =  0
      CMPW(alignb(d3, d2, 1));   // dw = +1
      CMPW(alignb(d3, d2, 2));   // dw = +2
      CMPW(alignb(d3, d2, 3));   // dw = +3
      CMPW(d3);                  // dw = +4
      CMPW(alignb(d4, d3, 1));   // dw = +5
      CMPW(alignb(d4, d3, 2));   // dw = +6
      CMPW(alignb(d4, d3, 3));   // dw = +7
      #undef CMPW
    }
    const int n0 = 225 - (int)( nm        & 0xff);
    const int n1 = 225 - (int)((nm >> 8)  & 0xff);
    const int n2 = 225 - (int)((nm >> 16) & 0xff);
    const int n3 = 225 - (int)((nm >> 24) & 0xff);
    acc += x0 * (225.0f / (float)n0);
    acc += x1 * (225.0f / (float)n1);
    acc += x2 * (225.0f / (float)n2);
    acc += x3 * (225.0f / (float)n3);
  }

  // ---- block reduction ----
  #pragma unroll
  for (int off = 32; off > 0; off >>= 1) acc += __shfl_down(acc, off, 64);
  const int lane = tid & 63, wv = tid >> 6;
  if (lane == 0) wpart[wv] = acc;
  __syncthreads();
  if (tid == 0) part[blk] = wpart[0] + wpart[1] + wpart[2] + wpart[3];
}

__global__ __launch_bounds__(256) void wce_reduce(const float* __restrict__ part,
                                                  float* __restrict__ out, int n) {
  __shared__ float wpart[4];
  float a = 0.0f;
  for (int i = threadIdx.x; i < n; i += 256) a += part[i];
  #pragma unroll
  for (int off = 32; off > 0; off >>= 1) a += __shfl_down(a, off, 64);
  const int lane = threadIdx.x & 63, wv = threadIdx.x >> 6;
  if (lane == 0) wpart[wv] = a;
  __syncthreads();
  if (threadIdx.x == 0) {
    const float tot = wpart[0] + wpart[1] + wpart[2] + wpart[3];
    out[0] = -tot / (float)NPIX;
  }
}

extern "C" void kernel_launch(void* const* d_in, const int* in_sizes, int n_in,
                              void* d_out, int out_size, void* d_ws, size_t ws_size,
                              hipStream_t stream) {
  const float* in = (const float*)d_in[0];
  const int*   tg = (const int*)d_in[1];
  float* out  = (float*)d_out;
  float* part = (float*)d_ws;

  wce_main<<<NBLK, 256, 0, stream>>>(in, tg, part);
  wce_reduce<<<1, 256, 0, stream>>>(part, out, NBLK);
}

// Round 7
// 55.949 us; speedup vs baseline: 1.4489x; 1.0763x over previous
//
#include <hip/hip_runtime.h>
#include <stdint.h>

#define BB 8
#define CC 19
#define HH 512
#define WW 1024
#define KK 15
#define RR 7
#define TH 8
#define NROWS (TH + 2*RR)          // 22 staged rows
#define ROW_DW 260                 // 2 pad dw + 256 data dw + 2 pad dw
#define NPIX (BB*HH*WW)            // 4194304
#define SENT4 0x1F1F1F1Fu          // sentinel class 31: xor with 0..18 stays in [1,31]

static __device__ __forceinline__ uint32_t alignb(uint32_t hi, uint32_t lo, unsigned s) {
#if __has_builtin(__builtin_amdgcn_alignbyte)
  return __builtin_amdgcn_alignbyte(hi, lo, s);
#else
  return (uint32_t)(((((uint64_t)hi) << 32) | lo) >> (8u * s));
#endif
}

__global__ __launch_bounds__(256) void wce_main(const float* __restrict__ in,
                                                const int* __restrict__ tg,
                                                float* __restrict__ part) {
  __shared__ uint32_t T[NROWS][ROW_DW];
  __shared__ float wpart[4];
  const int tid = threadIdx.x;
  const int blk = blockIdx.x;
  const int bb  = blk >> 6;           // 64 h-blocks per batch (512/TH)
  const int h0  = (blk & 63) * TH;

  // ---- stage 22 target rows as packed bytes with sentinel padding ----
  const int total = NROWS * ROW_DW;
  for (int idx = tid; idx < total; idx += 256) {
    const int r = idx / ROW_DW;
    const int d = idx - r * ROW_DW;
    uint32_t v = SENT4;
    const int h = h0 - RR + r;
    if (h >= 0 && h < HH && d >= 2 && d < 258) {
      const int4 t4 = *reinterpret_cast<const int4*>(&tg[(bb*HH + h)*WW + (d - 2)*4]);
      v = (uint32_t)(t4.x & 0xff)        | ((uint32_t)(t4.y & 0xff) << 8)
        | ((uint32_t)(t4.z & 0xff) << 16) | ((uint32_t)(t4.w & 0xff) << 24);
    }
    (&T[0][0])[idx] = v;
  }
  __syncthreads();

  const int g = tid;                  // this thread's 4-px group: w = 4g..4g+3
  float acc = 0.0f;

  #pragma unroll 1
  for (int s = 0; s < TH; ++s) {
    const int hh = h0 + s;
    const uint32_t c4 = T[s + RR][g + 2];   // center classes, packed bytes

    // issue the 4 input gathers early; they drain under the window compute
    const int c0 = (int)(c4 & 0xff), c1 = (int)((c4 >> 8) & 0xff);
    const int c2 = (int)((c4 >> 16) & 0xff), c3 = (int)((c4 >> 24) & 0xff);
    const int base = bb*CC*HH*WW + hh*WW + 4*g;
    const float x0 = in[base + c0*(HH*WW) + 0];
    const float x1 = in[base + c1*(HH*WW) + 1];
    const float x2 = in[base + c2*(HH*WW) + 2];
    const float x3 = in[base + c3*(HH*WW) + 3];

    // ---- SWAR non-match count over the 15x15 window ----
    uint32_t nm = 0;
    #pragma unroll
    for (int wr = 0; wr < KK; ++wr) {
      const uint32_t* row = &T[s + wr][g];  // dwords g..g+4 cover w = 4g-8 .. 4g+11
      const uint32_t d0 = row[0], d1 = row[1], d2 = row[2], d3 = row[3], d4 = row[4];
      #define CMPW(rhs) do { uint32_t t_ = ((rhs) ^ c4) + 0x7f7f7f7fu; \
                             nm += (t_ & 0x80808080u) >> 7; } while (0)
      CMPW(alignb(d1, d0, 1));   // dw = -7
      CMPW(alignb(d1, d0, 2));   // dw = -6
      CMPW(alignb(d1, d0, 3));   // dw = -5
      CMPW(d1);                  // dw = -4
      CMPW(alignb(d2, d1, 1));   // dw = -3
      CMPW(alignb(d2, d1, 2));   // dw = -2
      CMPW(alignb(d2, d1, 3));   // dw = -1
      CMPW(d2);                  // dw =  0
      CMPW(alignb(d3, d2, 1));   // dw = +1
      CMPW(alignb(d3, d2, 2));   // dw = +2
      CMPW(alignb(d3, d2, 3));   // dw = +3
      CMPW(d3);                  // dw = +4
      CMPW(alignb(d4, d3, 1));   // dw = +5
      CMPW(alignb(d4, d3, 2));   // dw = +6
      CMPW(alignb(d4, d3, 3));   // dw = +7
      #undef CMPW
    }
    const int n0 = 225 - (int)( nm        & 0xff);
    const int n1 = 225 - (int)((nm >> 8)  & 0xff);
    const int n2 = 225 - (int)((nm >> 16) & 0xff);
    const int n3 = 225 - (int)((nm >> 24) & 0xff);
    acc += x0 * (225.0f / (float)n0);
    acc += x1 * (225.0f / (float)n1);
    acc += x2 * (225.0f / (float)n2);
    acc += x3 * (225.0f / (float)n3);
  }

  // ---- block reduction ----
  #pragma unroll
  for (int off = 32; off > 0; off >>= 1) acc += __shfl_down(acc, off, 64);
  const int lane = tid & 63, wv = tid >> 6;
  if (lane == 0) wpart[wv] = acc;
  __syncthreads();
  if (tid == 0) part[blk] = wpart[0] + wpart[1] + wpart[2] + wpart[3];
}

__global__ __launch_bounds__(256) void wce_reduce(const float* __restrict__ part,
                                                  float* __restrict__ out, int n) {
  __shared__ float wpart[4];
  float a = 0.0f;
  for (int i = threadIdx.x; i < n; i += 256) a += part[i];
  #pragma unroll
  for (int off = 32; off > 0; off >>= 1) a += __shfl_down(a, off, 64);
  const int lane = threadIdx.x & 63, wv = threadIdx.x >> 6;
  if (lane == 0) wpart[wv] = a;
  __syncthreads();
  if (threadIdx.x == 0) {
    const float tot = wpart[0] + wpart[1] + wpart[2] + wpart[3];
    out[0] = -tot / (float)NPIX;
  }
}

extern "C" void kernel_launch(void* const* d_in, const int* in_sizes, int n_in,
                              void* d_out, int out_size, void* d_ws, size_t ws_size,
                              hipStream_t stream) {
  const float* in = (const float*)d_in[0];
  const int*   tg = (const int*)d_in[1];
  float* out  = (float*)d_out;
  float* part = (float*)d_ws;

  const int nblk = BB * (HH / TH);   // 512
  wce_main<<<nblk, 256, 0, stream>>>(in, tg, part);
  wce_reduce<<<1, 256, 0, stream>>>(part, out, nblk);
}